// Round 5
// baseline (156.887 us; speedup 1.0000x reference)
//
#include <hip/hip_runtime.h>

// B=256, F=32, N=16, D=512
//   sims[b,f,c,n] = relu(face[b,f]·ner[c,n])      (8192 x 4096 NT GEMM, K=512)
//   S_all[b,f]    = sum_{c,n} masked(sims)        (masked: ==1.0 -> 0)
//   pos[b,f]      = sum_n sims[b,f,b,n]           (unmasked diagonal)
//   diag_m[b,f]   = sum_n masked(sims[b,f,b,n])
//   loss = sum(relu((S_all-diag_m)/255 - pos + 0.2) * face_mask) / 256
//
// Round 5: barrier-free "flatmm" GEMM. One block per (1024-row M-chunk,
// 128-col ner panel); grid = 8*32 = 256 = one block per CU. B panel staged
// once into LDS (128 KiB, XOR k-slot swizzle, both-sides w/ global_load_lds);
// A-fragments stream global->VGPR (no LDS, no barriers in the K loop),
// 2-deep register double-buffer. Fused rowsum + diag extraction epilogue.

#define DIM_D 512
#define M_TOT 8192
#define N_TOT 4096

typedef __attribute__((ext_vector_type(8))) short short8v;
typedef __attribute__((ext_vector_type(4))) float f32x4;

__device__ __forceinline__ unsigned short f2bf(float f) {
  unsigned int u = __builtin_bit_cast(unsigned int, f);
  u += 0x7fffu + ((u >> 16) & 1u);
  return (unsigned short)(u >> 16);
}

// ---------------------------------------------------------------------------
// Merged cvt: face+ner fp32 -> bf16, plus face_mask (fp32 row-sum != 0).
// ---------------------------------------------------------------------------
__global__ __launch_bounds__(256) void cvt_all(
    const float* __restrict__ face, const float* __restrict__ ner,
    unsigned short* __restrict__ face_bf, unsigned short* __restrict__ ner_bf,
    float* __restrict__ mask) {
  const int gw = blockIdx.x * 4 + (threadIdx.x >> 6);
  const int lane = threadIdx.x & 63;
  const bool isFace = gw < M_TOT;
  const int row = isFace ? gw : gw - M_TOT;
  const float* src = (isFace ? face : ner) + (size_t)row * DIM_D;
  unsigned short* dst = (isFace ? face_bf : ner_bf) + (size_t)row * DIM_D;

  const float4 f0 = ((const float4*)src)[lane * 2];
  const float4 f1 = ((const float4*)src)[lane * 2 + 1];
  short8v o;
  o[0] = (short)f2bf(f0.x); o[1] = (short)f2bf(f0.y);
  o[2] = (short)f2bf(f0.z); o[3] = (short)f2bf(f0.w);
  o[4] = (short)f2bf(f1.x); o[5] = (short)f2bf(f1.y);
  o[6] = (short)f2bf(f1.z); o[7] = (short)f2bf(f1.w);
  *(short8v*)(dst + lane * 8) = o;

  if (isFace) {
    float fs = f0.x + f0.y + f0.z + f0.w + f1.x + f1.y + f1.z + f1.w;
#pragma unroll
    for (int off = 1; off < 64; off <<= 1) fs += __shfl_xor(fs, off);
    if (lane == 0) mask[row] = (fs != 0.0f) ? 1.0f : 0.0f;
  }
}

// ---------------------------------------------------------------------------
// Flat GEMM. 512 threads = 8 waves: wn = wid&1 (two 64-col groups),
// wm = wid>>1 (four 128-row groups). Two passes of 512 rows per block.
// LDS: ner panel [128 cols][64 slots of 16B]; slot s of col c holds global
// k-slot (s ^ (c&7))  -> ds_read_b128 2-way bank alias = free.
// ---------------------------------------------------------------------------
#define MFMA(A_, B_, C_) __builtin_amdgcn_mfma_f32_16x16x32_bf16(A_, B_, C_, 0, 0, 0)

#define GLDS(SRC, DSTOFF)                                                     \
  __builtin_amdgcn_global_load_lds(                                           \
      (const __attribute__((address_space(1))) void*)(SRC),                   \
      (__attribute__((address_space(3))) void*)(lds + (DSTOFF)), 16, 0, 0)

__global__ __launch_bounds__(512, 2) void grl_flat(
    const unsigned short* __restrict__ A, const unsigned short* __restrict__ Bn,
    float* __restrict__ S_all, float* __restrict__ pos,
    float* __restrict__ diagm) {
  extern __shared__ unsigned short lds[];  // 128 * 512 shorts = 128 KiB

  const int tid = threadIdx.x;
  const int lane = tid & 63;
  const int wid = tid >> 6;
  const int mc = blockIdx.x >> 5;  // 0..7   : 1024-row chunk of face
  const int p = blockIdx.x & 31;   // 0..31  : 128-col panel of ner
  const int wn = wid & 1;
  const int wm = wid >> 1;
  const int khl = lane >> 4;   // k-half-slot within fragment
  const int swz = lane & 7;    // reader swizzle key (== local col & 7)

  // ---- stage B panel: 16 global_load_lds per thread, LDS dst linear ----
  // instr i: local col = i*8 + wid (wave-uniform), lane -> slot = lane.
  // source k-slot = lane ^ (col&7) = lane ^ wid.
  const unsigned short* pB0 =
      Bn + (size_t)(p * 128 + wid) * DIM_D + (lane ^ wid) * 8;
#pragma unroll
  for (int i = 0; i < 16; ++i) GLDS(pB0 + (size_t)i * 8 * DIM_D, (i * 8 + wid) * 512);

  __syncthreads();  // drains vmcnt(0): panel resident; no barriers after this

  const int bcol = (wn * 64 + (lane & 15)) * 512;  // B reader col base (shorts)

#define LOADA(R, KT)                                                    \
  _Pragma("unroll") for (int mi_ = 0; mi_ < 8; ++mi_)                   \
      R[mi_] = *(const short8v*)(pA + mi_ * 8192 + (KT) * 32);

#define LOADB(R, KT)                                                    \
  _Pragma("unroll") for (int ni_ = 0; ni_ < 4; ++ni_)                   \
      R[ni_] = *(const short8v*)(lds + bcol + ni_ * 8192 +              \
                                 ((((KT) * 4 + khl) ^ swz) * 8));

#define MF32(AR, BR)                                                    \
  _Pragma("unroll") for (int ni_ = 0; ni_ < 4; ++ni_)                   \
      _Pragma("unroll") for (int mi_ = 0; mi_ < 8; ++mi_)               \
          acc[mi_][ni_] = MFMA(AR[mi_], BR[ni_], acc[mi_][ni_]);

  for (int ps = 0; ps < 2; ++ps) {
    const unsigned short* pA =
        A + (size_t)(mc * 1024 + ps * 512 + wm * 128 + (lane & 15)) * DIM_D +
        khl * 8;

    f32x4 acc[8][4];
#pragma unroll
    for (int i = 0; i < 8; ++i)
#pragma unroll
      for (int j = 0; j < 4; ++j) acc[i][j] = (f32x4){0.f, 0.f, 0.f, 0.f};

    short8v aX[8], aY[8], b[4];
    LOADA(aX, 0);
#pragma unroll
    for (int kt = 0; kt < 16; ++kt) {
      if (kt < 15) {
        if (kt & 1) { LOADA(aX, kt + 1); }
        else        { LOADA(aY, kt + 1); }
      }
      LOADB(b, kt);
      if (kt & 1) { MF32(aY, b); }
      else        { MF32(aX, b); }
    }

    // ---- fused epilogue: relu + (==1 -> 0) + row sums + diagonal -------
    // C/D layout: col = lane&15 (n), row(frag) = (lane>>4)*4 + reg
#pragma unroll
    for (int mi = 0; mi < 8; ++mi) {
      const int R0 = mc * 1024 + ps * 512 + wm * 128 + mi * 16;
      float rs[4] = {0.f, 0.f, 0.f, 0.f};
#pragma unroll
      for (int ni = 0; ni < 4; ++ni)
#pragma unroll
        for (int r = 0; r < 4; ++r) {
          float v = acc[mi][ni][r];
          v = v > 0.0f ? v : 0.0f;
          v = (v == 1.0f) ? 0.0f : v;
          rs[r] += v;
        }
#pragma unroll
      for (int r = 0; r < 4; ++r) {
        float s = rs[r];
        s += __shfl_xor(s, 1);
        s += __shfl_xor(s, 2);
        s += __shfl_xor(s, 4);
        s += __shfl_xor(s, 8);
        if ((lane & 15) == 0)
          atomicAdd(&S_all[R0 + (lane >> 4) * 4 + r], s);
      }
      // diagonal: rows R0..R0+15 share b_ = R0>>5; diag cols [16b_,16b_+16)
      const int b_ = R0 >> 5;
      const int tc = b_ * 16 - p * 128;  // panel-local col offset
      if (tc >= 0 && tc < 128 && (tc >> 6) == wn) {
        const int dn = (tc >> 4) & 3;
#pragma unroll
        for (int ni = 0; ni < 4; ++ni)
          if (ni == dn) {
#pragma unroll
            for (int r = 0; r < 4; ++r) {
              float v = acc[mi][ni][r];
              v = v > 0.0f ? v : 0.0f;
              float vm = (v == 1.0f) ? 0.0f : v;
              float psum = v, dsum = vm;
              psum += __shfl_xor(psum, 1); dsum += __shfl_xor(dsum, 1);
              psum += __shfl_xor(psum, 2); dsum += __shfl_xor(dsum, 2);
              psum += __shfl_xor(psum, 4); dsum += __shfl_xor(dsum, 4);
              psum += __shfl_xor(psum, 8); dsum += __shfl_xor(dsum, 8);
              if ((lane & 15) == 0) {
                const int R = R0 + (lane >> 4) * 4 + r;
                pos[R] = psum;
                diagm[R] = dsum;
              }
            }
          }
      }
    }
  }
}

// ---------------------------------------------------------------------------
// Finalize: rank + global sum. Single block, 1024 threads.
// ---------------------------------------------------------------------------
__global__ __launch_bounds__(1024) void grl_final(
    const float* __restrict__ S_all, const float* __restrict__ diagm,
    const float* __restrict__ pos, const float* __restrict__ mask,
    float* __restrict__ out) {
  __shared__ float red[16];
  const int lane = threadIdx.x & 63;
  const int wv = threadIdx.x >> 6;
  float s = 0.0f;
  for (int r = threadIdx.x; r < M_TOT; r += 1024) {
    const float neg = (S_all[r] - diagm[r]) / 255.0f;  // 255 + 1e-8 == 255.0f
    float rank = neg - pos[r] + 0.2f;
    rank = rank > 0.0f ? rank : 0.0f;
    s += rank * mask[r];
  }
#pragma unroll
  for (int off = 1; off < 64; off <<= 1) s += __shfl_xor(s, off);
  if (lane == 0) red[wv] = s;
  __syncthreads();
  if (threadIdx.x == 0) {
    float t = 0.0f;
#pragma unroll
    for (int i = 0; i < 16; ++i) t += red[i];
    out[0] = t / 256.0f;  // BETA * sum / B
  }
}

// ---------------------------------------------------------------------------
extern "C" void kernel_launch(void* const* d_in, const int* in_sizes, int n_in,
                              void* d_out, int out_size, void* d_ws, size_t ws_size,
                              hipStream_t stream) {
  const float* face = (const float*)d_in[0];
  const float* ner = (const float*)d_in[1];

  unsigned short* face_bf = (unsigned short*)d_ws;
  unsigned short* ner_bf = face_bf + (size_t)M_TOT * DIM_D;
  float* S_all = (float*)(ner_bf + (size_t)N_TOT * DIM_D);
  float* diagm = S_all + M_TOT;
  float* pos = diagm + M_TOT;
  float* mask = pos + M_TOT;

  hipFuncSetAttribute((const void*)grl_flat,
                      hipFuncAttributeMaxDynamicSharedMemorySize, 131072);

  hipMemsetAsync(S_all, 0, M_TOT * sizeof(float), stream);
  cvt_all<<<(M_TOT + N_TOT) / 4, 256, 0, stream>>>(face, ner, face_bf, ner_bf,
                                                   mask);
  grl_flat<<<256, 512, 131072, stream>>>(face_bf, ner_bf, S_all, pos, diagm);
  grl_final<<<1, 1024, 0, stream>>>(S_all, diagm, pos, mask, (float*)d_out);
}

// Round 6
// 71.179 us; speedup vs baseline: 2.2041x; 2.2041x over previous
//
#include <hip/hip_runtime.h>

// B=256, F=32, N=16, D=512
//   sims[b,f,c,n] = relu(face[b,f]·ner[c,n])      (8192 x 4096 NT GEMM, K=512)
//   S_all[b,f]    = sum_{c,n} masked(sims)        (masked: ==1.0 -> 0)
//   pos[b,f]      = sum_n sims[b,f,b,n]           (unmasked diagonal)
//   diag_m[b,f]   = sum_n masked(sims[b,f,b,n])
//   loss = sum(relu((S_all-diag_m)/255 - pos + 0.2) * face_mask) / 256
//
// Round 6: revert flat design (spilled). Round-2 proven 128x128 2-barrier
// loop upgraded to BK=64 (32 MFMA per barrier pair, 32 KB LDS, 4-5 blk/CU),
// 8-slot XOR k-swizzle (both-sides w/ global_load_lds), LDS-transpose
// rowsum epilogue (no shfl chains), fused diag extraction, merged cvt.

#define DIM_D 512
#define M_TOT 8192
#define N_TOT 4096

typedef __attribute__((ext_vector_type(8))) short short8v;
typedef __attribute__((ext_vector_type(4))) float f32x4;

__device__ __forceinline__ unsigned short f2bf(float f) {
  unsigned int u = __builtin_bit_cast(unsigned int, f);
  u += 0x7fffu + ((u >> 16) & 1u);
  return (unsigned short)(u >> 16);
}

// ---------------------------------------------------------------------------
// Merged cvt: face+ner fp32 -> bf16, plus face_mask (fp32 row-sum != 0).
// ---------------------------------------------------------------------------
__global__ __launch_bounds__(256) void cvt_all(
    const float* __restrict__ face, const float* __restrict__ ner,
    unsigned short* __restrict__ face_bf, unsigned short* __restrict__ ner_bf,
    float* __restrict__ mask) {
  const int gw = blockIdx.x * 4 + (threadIdx.x >> 6);
  const int lane = threadIdx.x & 63;
  const bool isFace = gw < M_TOT;
  const int row = isFace ? gw : gw - M_TOT;
  const float* src = (isFace ? face : ner) + (size_t)row * DIM_D;
  unsigned short* dst = (isFace ? face_bf : ner_bf) + (size_t)row * DIM_D;

  const float4 f0 = ((const float4*)src)[lane * 2];
  const float4 f1 = ((const float4*)src)[lane * 2 + 1];
  short8v o;
  o[0] = (short)f2bf(f0.x); o[1] = (short)f2bf(f0.y);
  o[2] = (short)f2bf(f0.z); o[3] = (short)f2bf(f0.w);
  o[4] = (short)f2bf(f1.x); o[5] = (short)f2bf(f1.y);
  o[6] = (short)f2bf(f1.z); o[7] = (short)f2bf(f1.w);
  *(short8v*)(dst + lane * 8) = o;

  if (isFace) {
    float fs = f0.x + f0.y + f0.z + f0.w + f1.x + f1.y + f1.z + f1.w;
#pragma unroll
    for (int off = 1; off < 64; off <<= 1) fs += __shfl_xor(fs, off);
    if (lane == 0) mask[row] = (fs != 0.0f) ? 1.0f : 0.0f;
  }
}

// ---------------------------------------------------------------------------
// 128x128 bf16 MFMA GEMM, BK=64, 4 waves (2x2), per-wave 64x64 = 4x4 frags.
// LDS per tile: A[128 rows][8 slots of 16B] + B same = 32 KB, single buffer.
// slot s of row r holds global k-slot (s ^ (r&7)); reader applies same XOR.
// Staged with 8x global_load_lds width=16 (dst linear, source pre-swizzled).
// ---------------------------------------------------------------------------
#define MFMA(A_, B_, C_) __builtin_amdgcn_mfma_f32_16x16x32_bf16(A_, B_, C_, 0, 0, 0)

#define GLDS(SRC, DSTOFF)                                                     \
  __builtin_amdgcn_global_load_lds(                                           \
      (const __attribute__((address_space(1))) void*)(SRC),                   \
      (__attribute__((address_space(3))) void*)(lds + (DSTOFF)), 16, 0, 0)

__global__ __launch_bounds__(256) void grl_gemm128(
    const unsigned short* __restrict__ A, const unsigned short* __restrict__ Bn,
    float* __restrict__ S_all, float* __restrict__ pos,
    float* __restrict__ diagm) {
  extern __shared__ unsigned short lds[];  // A: [0,8192) shorts, B: [8192,16384)

  const int tid = threadIdx.x;
  const int lane = tid & 63;
  const int wid = tid >> 6;
  const int wr = wid >> 1;   // 0..1 (M)
  const int wc = wid & 1;    // 0..1 (N)
  const int bx = blockIdx.x;
  const int by = blockIdx.y;
  const int m0 = bx * 128;
  const int n0 = by * 128;

  // ---- stager: instr i covers rows [i*32, i*32+32) ----------------------
  // lane -> row = i*32 + wid*8 + (lane>>3), slot = lane&7;
  // source k-slot g = slot ^ (row&7) = (lane&7) ^ (lane>>3)
  const int g = (lane & 7) ^ (lane >> 3);
  const int srow = wid * 8 + (lane >> 3);
  const unsigned short* gA = A + (size_t)(m0 + srow) * DIM_D + g * 8;
  const unsigned short* gB = Bn + (size_t)(n0 + srow) * DIM_D + g * 8;
  const int lbase = wid * 512;  // shorts; + i*2048 per instr

  // ---- reader: frag (row tile_r + (lane&15), k-slot ks*4 + (lane>>4)) ---
  // swizzled slot' = (ks*4 + (lane>>4)) ^ (lane&7)
  const int s0 = ((lane >> 4) ^ (lane & 7)) * 8;        // ks=0, shorts
  const int s1 = ((4 + (lane >> 4)) ^ (lane & 7)) * 8;  // ks=1
  const int rbase = (lane & 15) * 64;                   // row part, shorts

  f32x4 acc[4][4];
#pragma unroll
  for (int i = 0; i < 4; ++i)
#pragma unroll
    for (int j = 0; j < 4; ++j) acc[i][j] = (f32x4){0.f, 0.f, 0.f, 0.f};

  for (int t = 0; t < 8; ++t) {
    const int kofs = t * 64;
#pragma unroll
    for (int i = 0; i < 4; ++i) {
      GLDS(gA + kofs + (size_t)i * 32 * DIM_D, i * 2048 + lbase);
      GLDS(gB + kofs + (size_t)i * 32 * DIM_D, 8192 + i * 2048 + lbase);
    }
    __syncthreads();  // drains vmcnt(0): tile resident

#pragma unroll
    for (int ks = 0; ks < 2; ++ks) {
      const int so = ks ? s1 : s0;
      short8v a[4], b[4];
#pragma unroll
      for (int mi = 0; mi < 4; ++mi)
        a[mi] = *(const short8v*)(lds + (wr * 64 + mi * 16) * 64 + rbase + so);
#pragma unroll
      for (int ni = 0; ni < 4; ++ni)
        b[ni] = *(const short8v*)(lds + 8192 + (wc * 64 + ni * 16) * 64 + rbase + so);
#pragma unroll
      for (int mi = 0; mi < 4; ++mi)
#pragma unroll
        for (int ni = 0; ni < 4; ++ni)
          acc[mi][ni] = MFMA(a[mi], b[ni], acc[mi][ni]);
    }
    __syncthreads();  // compute done before next stage overwrites
  }

  // ---- fused relu + (==1 -> 0) + per-thread row sums --------------------
  // C/D layout: col = lane&15 (n), row(frag) = (lane>>4)*4 + reg
  float rs[4][4];  // [mi][reg]
#pragma unroll
  for (int mi = 0; mi < 4; ++mi)
#pragma unroll
    for (int r = 0; r < 4; ++r) rs[mi][r] = 0.0f;
#pragma unroll
  for (int mi = 0; mi < 4; ++mi)
#pragma unroll
    for (int ni = 0; ni < 4; ++ni)
#pragma unroll
      for (int r = 0; r < 4; ++r) {
        float v = acc[mi][ni][r];
        v = v > 0.0f ? v : 0.0f;
        v = (v == 1.0f) ? 0.0f : v;
        rs[mi][r] += v;
      }

  // ---- diagonal extraction (blocks with by == bx>>1 only) ---------------
  if (by == (bx >> 1)) {
#pragma unroll
    for (int mi = 0; mi < 4; ++mi) {
      const int R0 = m0 + wr * 64 + mi * 16;  // rows R0..R0+15 share b_
      const int tc = ((R0 >> 5) << 4) - n0;   // in [0,128)
      if ((tc >> 6) == wc) {
        const int dn = (tc >> 4) & 3;
#pragma unroll
        for (int ni = 0; ni < 4; ++ni)
          if (ni == dn) {
#pragma unroll
            for (int r = 0; r < 4; ++r) {
              float v = acc[mi][ni][r];
              v = v > 0.0f ? v : 0.0f;
              float vm = (v == 1.0f) ? 0.0f : v;
              float ps = v, ds = vm;
              ps += __shfl_xor(ps, 1); ds += __shfl_xor(ds, 1);
              ps += __shfl_xor(ps, 2); ds += __shfl_xor(ds, 2);
              ps += __shfl_xor(ps, 4); ds += __shfl_xor(ds, 4);
              ps += __shfl_xor(ps, 8); ds += __shfl_xor(ds, 8);
              if ((lane & 15) == 0) {
                const int R = R0 + (lane >> 4) * 4 + r;
                pos[R] = ps;
                diagm[R] = ds;
              }
            }
          }
      }
    }
  }

  // ---- LDS-transpose row-sum reduce: 1 atomic per row per block ---------
  float* part = (float*)lds;  // [128][33] floats = 16.9 KB (K-loop done)
  const int c = wc * 16 + (lane & 15);
#pragma unroll
  for (int mi = 0; mi < 4; ++mi)
#pragma unroll
    for (int r = 0; r < 4; ++r) {
      const int rl = wr * 64 + mi * 16 + (lane >> 4) * 4 + r;
      part[rl * 33 + c] = rs[mi][r];
    }
  __syncthreads();
  if (tid < 128) {
    float s = 0.0f;
#pragma unroll
    for (int k = 0; k < 32; ++k) s += part[tid * 33 + k];
    atomicAdd(&S_all[m0 + tid], s);
  }
}

// ---------------------------------------------------------------------------
// Finalize: rank + global sum. Single block, 1024 threads.
// ---------------------------------------------------------------------------
__global__ __launch_bounds__(1024) void grl_final(
    const float* __restrict__ S_all, const float* __restrict__ diagm,
    const float* __restrict__ pos, const float* __restrict__ mask,
    float* __restrict__ out) {
  __shared__ float red[16];
  const int lane = threadIdx.x & 63;
  const int wv = threadIdx.x >> 6;
  float s = 0.0f;
  for (int r = threadIdx.x; r < M_TOT; r += 1024) {
    const float neg = (S_all[r] - diagm[r]) / 255.0f;  // 255 + 1e-8 == 255.0f
    float rank = neg - pos[r] + 0.2f;
    rank = rank > 0.0f ? rank : 0.0f;
    s += rank * mask[r];
  }
#pragma unroll
  for (int off = 1; off < 64; off <<= 1) s += __shfl_xor(s, off);
  if (lane == 0) red[wv] = s;
  __syncthreads();
  if (threadIdx.x == 0) {
    float t = 0.0f;
#pragma unroll
    for (int i = 0; i < 16; ++i) t += red[i];
    out[0] = t / 256.0f;  // BETA * sum / B
  }
}

// ---------------------------------------------------------------------------
extern "C" void kernel_launch(void* const* d_in, const int* in_sizes, int n_in,
                              void* d_out, int out_size, void* d_ws, size_t ws_size,
                              hipStream_t stream) {
  const float* face = (const float*)d_in[0];
  const float* ner = (const float*)d_in[1];

  unsigned short* face_bf = (unsigned short*)d_ws;
  unsigned short* ner_bf = face_bf + (size_t)M_TOT * DIM_D;
  float* S_all = (float*)(ner_bf + (size_t)N_TOT * DIM_D);
  float* diagm = S_all + M_TOT;
  float* pos = diagm + M_TOT;
  float* mask = pos + M_TOT;

  hipFuncSetAttribute((const void*)grl_gemm128,
                      hipFuncAttributeMaxDynamicSharedMemorySize, 32768);

  hipMemsetAsync(S_all, 0, M_TOT * sizeof(float), stream);
  cvt_all<<<(M_TOT + N_TOT) / 4, 256, 0, stream>>>(face, ner, face_bf, ner_bf,
                                                   mask);
  grl_gemm128<<<dim3(M_TOT / 128, N_TOT / 128), 256, 32768, stream>>>(
      face_bf, ner_bf, S_all, pos, diagm);
  grl_final<<<1, 1024, 0, stream>>>(S_all, diagm, pos, mask, (float*)d_out);
}